// Round 4
// baseline (1368.314 us; speedup 1.0000x reference)
//
#include <hip/hip_runtime.h>
#include <cstdint>
#include <cstddef>

// Problem dims
#define NF 64
#define NH 256
#define NW 256
#define NC 64
#define HOUT 254
#define WOUT 254
#define JR 32                 // output rows per block strip
#define NBLK (NF * 8)         // 512 blocks -> 2 blocks/CU

// ---------------- input-encoding detection (d_ws[0]) ----------------
// 1 = int32 values, 2 = float32 values
__global__ void detect_kernel(const unsigned int* __restrict__ x,
                              int* __restrict__ flagp) {
    if (threadIdx.x != 0 || blockIdx.x != 0) return;
    int c32 = 0, cf = 0;
    for (int i = 0; i < 64; ++i) {
        unsigned int v = x[i];
        unsigned int hi = v >> 8;
        if (hi == 0u || hi == 0x00FFFFFFu) c32++;   // int32 in [-128,127]
        float f = __uint_as_float(v);
        if (f == truncf(f) && f >= -129.0f && f <= 128.0f &&
            (v == 0u || fabsf(f) >= 1.0f)) cf++;    // small integral float
    }
    flagp[0] = (c32 == 64) ? 1 : ((cf == 64) ? 2 : 0);
}

__device__ __forceinline__ int dot4(int a, int b, int c) {
#if __has_builtin(__builtin_amdgcn_sdot4)
    return __builtin_amdgcn_sdot4(a, b, c, false);
#else
    #pragma unroll
    for (int i = 0; i < 4; ++i)
        c += (int)(signed char)(a >> (8 * i)) * (int)(signed char)(b >> (8 * i));
    return c;
#endif
}

template <typename T> struct V4;
template <> struct V4<int>   { using t = int4; };
template <> struct V4<float> { using t = float4; };

__device__ __forceinline__ int pk(int4 v) {
    return (v.x & 255) | ((v.y & 255) << 8) | ((v.z & 255) << 16) |
           ((v.w & 255) << 24);
}
__device__ __forceinline__ int pk(float4 v) {
    return ((int)v.x & 255) | (((int)v.y & 255) << 8) |
           (((int)v.z & 255) << 16) | (((int)v.w & 255) << 24);
}

// LDS row buffer layout (per row, 4096 dwords = 16 KB):
//   dword[(q4)*1024 + col*4 + qlo] = packed ch [16*q4+4*qlo .. +4) of col.
// Compute: ds_read_b128 at int4 index q4*256 + col (dense, 16B aligned).
// Staging: thread owns chunks c = i*256+tid (16 values each) ->
//   one ds_write_b128 at dword (c&3)*1024 + (c>>2)*4. Lanes t,t+32 collide
//   2-way on banks only (free per m136).
template <typename T>
__device__ __forceinline__ void conv_body(
    const T* __restrict__ x, const T* __restrict__ w,
    const int* __restrict__ bias, const int* __restrict__ qmp,
    const int* __restrict__ exp_p, const int* __restrict__ zpp,
    int* __restrict__ out) {
    __shared__ int xlds[4 * 4096];   // 4 rotating packed row buffers (64 KB)
    __shared__ int wlds[144];        // packed weights for this f

    const int tid = threadIdx.x;
    const int bid = blockIdx.x;
    const int f = bid >> 3;
    const int j0 = (bid & 7) * JR;
    const int nout = min(JR, HOUT - j0);
    using VT = typename V4<T>::t;

    // weights -> packed LDS (broadcast reads later: conflict-free)
    if (tid < 144) {
        VT v = *(const VT*)(w + (size_t)f * 576 + tid * 4);
        wlds[tid] = pk(v);
    }

    const int qm = qmp[0], ex = exp_p[0], zp = zpp[0];
    const int rmant = (qm < 2147418112) ? ((qm + 32768) >> 16) : 32767;
    const int tsh = 15 - ex;
    const long long rnd = 1LL << (tsh - 1);
    const int bv = bias[f];
    const size_t rowstride = (size_t)NW * NC;
    const T* xs = x + ((size_t)f * NH + j0) * rowstride;

    // prologue: load + pack row j0
    int4 P[4];
    {
        VT L[16];
        #pragma unroll
        for (int i = 0; i < 4; ++i) {
            const int c = i * 256 + tid;
            #pragma unroll
            for (int jj = 0; jj < 4; ++jj)
                L[i * 4 + jj] = *(const VT*)(xs + (size_t)c * 16 + jj * 4);
        }
        #pragma unroll
        for (int i = 0; i < 4; ++i)
            P[i] = make_int4(pk(L[i * 4]), pk(L[i * 4 + 1]),
                             pk(L[i * 4 + 2]), pk(L[i * 4 + 3]));
    }

    for (int r = 0; r <= nout + 1; ++r) {
        // ---- write row j0+r (packed last iter) into buffer r&3 ----
        {
            int* dst = xlds + (r & 3) * 4096;
            #pragma unroll
            for (int i = 0; i < 4; ++i) {
                const int c = i * 256 + tid;
                *(int4*)&dst[(c & 3) * 1024 + (c >> 2) * 4] = P[i];
            }
        }
        __syncthreads();

        const bool more = (r + 1 <= nout + 1);
        // ---- issue next row's loads; wait only at pack (end of iter) ----
        VT L[16];
        if (more) {
            const T* src = xs + (size_t)(r + 1) * rowstride;
            #pragma unroll
            for (int i = 0; i < 4; ++i) {
                const int c = i * 256 + tid;
                #pragma unroll
                for (int jj = 0; jj < 4; ++jj)
                    L[i * 4 + jj] = *(const VT*)(src + (size_t)c * 16 + jj * 4);
            }
        }

        // ---- compute output row j0+r-2 from buffers (r-2..r)&3 ----
        if (r >= 2 && tid < WOUT) {
            int a0 = 0, a1 = 0, a2 = 0, a3 = 0;
            #pragma unroll
            for (int m = 0; m < 3; ++m) {
                const int4* bm = (const int4*)(xlds + ((r - 2 + m) & 3) * 4096);
                #pragma unroll
                for (int n = 0; n < 3; ++n) {
                    #pragma unroll
                    for (int q4 = 0; q4 < 4; ++q4) {
                        int4 xv = bm[q4 * 256 + tid + n];
                        int4 wv = *(const int4*)&wlds[(m * 3 + n) * 16 + q4 * 4];
                        a0 = dot4(xv.x, wv.x, a0);
                        a1 = dot4(xv.y, wv.y, a1);
                        a2 = dot4(xv.z, wv.z, a2);
                        a3 = dot4(xv.w, wv.w, a3);
                    }
                }
            }
            long long a = (long long)(a0 + a1 + a2 + a3 + bv) * rmant + rnd;
            long long res = (a >> tsh) + zp;
            res = res < -128 ? -128 : (res > 127 ? 127 : res);
            out[((size_t)f * HOUT + (j0 + r - 2)) * WOUT + tid] = (int)res;
        }

        // ---- pack next row (s_waitcnt vmcnt lands here, latency hidden) ----
        if (more) {
            #pragma unroll
            for (int i = 0; i < 4; ++i)
                P[i] = make_int4(pk(L[i * 4]), pk(L[i * 4 + 1]),
                                 pk(L[i * 4 + 2]), pk(L[i * 4 + 3]));
        }
    }
}

__global__ __launch_bounds__(256, 2) void conv_i32(
    const int* __restrict__ x, const int* __restrict__ w,
    const int* __restrict__ bias, const int* __restrict__ qmp,
    const int* __restrict__ exp_p, const int* __restrict__ zpp,
    int* __restrict__ out, const int* __restrict__ flagp) {
    if (flagp[0] != 1) return;
    conv_body<int>(x, w, bias, qmp, exp_p, zpp, out);
}

__global__ __launch_bounds__(256, 2) void conv_f32(
    const float* __restrict__ x, const float* __restrict__ w,
    const int* __restrict__ bias, const int* __restrict__ qmp,
    const int* __restrict__ exp_p, const int* __restrict__ zpp,
    int* __restrict__ out, const int* __restrict__ flagp) {
    if (flagp[0] != 2) return;
    conv_body<float>(x, w, bias, qmp, exp_p, zpp, out);
}

extern "C" void kernel_launch(void* const* d_in, const int* in_sizes, int n_in,
                              void* d_out, int out_size, void* d_ws,
                              size_t ws_size, hipStream_t stream) {
    (void)in_sizes; (void)n_in; (void)ws_size; (void)out_size;
    const void* x = d_in[0];
    const void* w = d_in[1];
    const int* bias = (const int*)d_in[2];
    const int* qm = (const int*)d_in[3];
    const int* ex = (const int*)d_in[4];
    const int* zp = (const int*)d_in[5];
    int* out = (int*)d_out;
    int* flagp = (int*)d_ws;

    detect_kernel<<<1, 64, 0, stream>>>((const unsigned int*)x, flagp);
    conv_i32<<<NBLK, 256, 0, stream>>>((const int*)x, (const int*)w,
                                       bias, qm, ex, zp, out, flagp);
    conv_f32<<<NBLK, 256, 0, stream>>>((const float*)x, (const float*)w,
                                       bias, qm, ex, zp, out, flagp);
}

// Round 5
// 1350.375 us; speedup vs baseline: 1.0133x; 1.0133x over previous
//
#include <hip/hip_runtime.h>
#include <cstdint>
#include <cstddef>

// Problem dims
#define NF 64
#define NH 256
#define NW 256
#define NC 64
#define HOUT 254
#define WOUT 254
#define JR 32                 // output rows per block strip
#define NBLK (NF * 8)         // 512 blocks -> 2 blocks/CU

// ---------------- input-encoding detection (d_ws[0]) ----------------
// 1 = int32 values, 2 = float32 values
__global__ void detect_kernel(const unsigned int* __restrict__ x,
                              int* __restrict__ flagp) {
    if (threadIdx.x != 0 || blockIdx.x != 0) return;
    int c32 = 0, cf = 0;
    for (int i = 0; i < 64; ++i) {
        unsigned int v = x[i];
        unsigned int hi = v >> 8;
        if (hi == 0u || hi == 0x00FFFFFFu) c32++;   // int32 in [-128,127]
        float f = __uint_as_float(v);
        if (f == truncf(f) && f >= -129.0f && f <= 128.0f &&
            (v == 0u || fabsf(f) >= 1.0f)) cf++;    // small integral float
    }
    flagp[0] = (c32 == 64) ? 1 : ((cf == 64) ? 2 : 0);
}

__device__ __forceinline__ int dot4(int a, int b, int c) {
#if __has_builtin(__builtin_amdgcn_sdot4)
    return __builtin_amdgcn_sdot4(a, b, c, false);
#else
    #pragma unroll
    for (int i = 0; i < 4; ++i)
        c += (int)(signed char)(a >> (8 * i)) * (int)(signed char)(b >> (8 * i));
    return c;
#endif
}

template <typename T> struct V4;
template <> struct V4<int>   { using t = int4; };
template <> struct V4<float> { using t = float4; };

__device__ __forceinline__ int pk(int4 v) {
    return (v.x & 255) | ((v.y & 255) << 8) | ((v.z & 255) << 16) |
           ((v.w & 255) << 24);
}
__device__ __forceinline__ int pk(float4 v) {
    return ((int)v.x & 255) | (((int)v.y & 255) << 8) |
           (((int)v.z & 255) << 16) | (((int)v.w & 255) << 24);
}

// LDS packed-row layout (per row, 4096 dwords = 16 KB), group g = 4 channels:
//   dword addr(g) = ((g>>2)&3)*1024 + (g>>4)*4 + (g&3)
// i.e. int4 (q4, col) = channels [16*q4, 16*q4+16) of col. Compute does
// ds_read_b128 at int4 index q4*256 + col (dense, 16B-aligned, m134 pattern).
//
// Global staging is fully coalesced: wave wv, instr q, lane l loads the 16-B
// group s = wv*1024 + q*64 + l  -> each instruction covers one contiguous
// 1 KB segment (16 B/lane). The thread then owns 16 scattered groups and
// scatters them to LDS with 16 ds_write_b32 (4-way bank alias on writes:
// ~1.58x on 64 wave-instrs per block-row = ~2% of the row budget).
template <typename T>
__device__ __forceinline__ void conv_body(
    const T* __restrict__ x, const T* __restrict__ w,
    const int* __restrict__ bias, const int* __restrict__ qmp,
    const int* __restrict__ exp_p, const int* __restrict__ zpp,
    int* __restrict__ out) {
    __shared__ int xlds[4 * 4096];   // 4 rotating packed row buffers (64 KB)
    __shared__ int wlds[144];        // packed weights for this f

    const int tid = threadIdx.x;
    const int bid = blockIdx.x;
    const int f = bid >> 3;
    const int j0 = (bid & 7) * JR;
    const int nout = min(JR, HOUT - j0);
    using VT = typename V4<T>::t;

    // weights -> packed LDS (broadcast reads later: conflict-free)
    if (tid < 144) {
        VT v = *(const VT*)(w + (size_t)f * 576 + tid * 4);
        wlds[tid] = pk(v);
    }

    const int qm = qmp[0], ex = exp_p[0], zp = zpp[0];
    const int rmant = (qm < 2147418112) ? ((qm + 32768) >> 16) : 32767;
    const int tsh = 15 - ex;
    const long long rnd = 1LL << (tsh - 1);
    const int bv = bias[f];
    const size_t rowstride = (size_t)NW * NC;
    const T* xs = x + ((size_t)f * NH + j0) * rowstride;

    const int wv = tid >> 6, ln = tid & 63;
    const int sbase = wv * 1024 + ln;                 // group index base
    const int wbase = ((ln >> 2) & 3) * 1024 +        // LDS dword base
                      (wv * 64 + (ln >> 4)) * 4 + (ln & 3);

    // prologue: load + pack row j0 (coalesced: 1 KB contiguous per instr)
    int P[16];
    {
        VT L[16];
        #pragma unroll
        for (int q = 0; q < 16; ++q)
            L[q] = *(const VT*)(xs + (size_t)(sbase + q * 64) * 4);
        #pragma unroll
        for (int q = 0; q < 16; ++q)
            P[q] = pk(L[q]);
    }

    for (int r = 0; r <= nout + 1; ++r) {
        // ---- scatter row j0+r (packed last iter) into buffer r&3 ----
        {
            int* dst = xlds + (r & 3) * 4096;
            #pragma unroll
            for (int q = 0; q < 16; ++q)
                dst[wbase + q * 16] = P[q];
        }
        __syncthreads();

        const bool more = (r + 1 <= nout + 1);
        // ---- issue next row's loads; wait lands at pack (end of iter) ----
        VT L[16];
        if (more) {
            const T* src = xs + (size_t)(r + 1) * rowstride;
            #pragma unroll
            for (int q = 0; q < 16; ++q)
                L[q] = *(const VT*)(src + (size_t)(sbase + q * 64) * 4);
        }

        // ---- compute output row j0+r-2 from buffers (r-2..r)&3 ----
        if (r >= 2 && tid < WOUT) {
            int a0 = 0, a1 = 0, a2 = 0, a3 = 0;
            #pragma unroll
            for (int m = 0; m < 3; ++m) {
                const int4* bm = (const int4*)(xlds + ((r - 2 + m) & 3) * 4096);
                #pragma unroll
                for (int n = 0; n < 3; ++n) {
                    #pragma unroll
                    for (int q4 = 0; q4 < 4; ++q4) {
                        int4 xv = bm[q4 * 256 + tid + n];
                        int4 wvv = *(const int4*)&wlds[(m * 3 + n) * 16 + q4 * 4];
                        a0 = dot4(xv.x, wvv.x, a0);
                        a1 = dot4(xv.y, wvv.y, a1);
                        a2 = dot4(xv.z, wvv.z, a2);
                        a3 = dot4(xv.w, wvv.w, a3);
                    }
                }
            }
            long long a = (long long)(a0 + a1 + a2 + a3 + bv) * rmant + rnd;
            long long res = (a >> tsh) + zp;
            res = res < -128 ? -128 : (res > 127 ? 127 : res);
            out[((size_t)f * HOUT + (j0 + r - 2)) * WOUT + tid] = (int)res;
        }

        // ---- pack next row (s_waitcnt vmcnt lands here, latency hidden) ----
        if (more) {
            #pragma unroll
            for (int q = 0; q < 16; ++q)
                P[q] = pk(L[q]);
        }
    }
}

__global__ __launch_bounds__(256, 2) void conv_i32(
    const int* __restrict__ x, const int* __restrict__ w,
    const int* __restrict__ bias, const int* __restrict__ qmp,
    const int* __restrict__ exp_p, const int* __restrict__ zpp,
    int* __restrict__ out, const int* __restrict__ flagp) {
    if (flagp[0] != 1) return;
    conv_body<int>(x, w, bias, qmp, exp_p, zpp, out);
}

__global__ __launch_bounds__(256, 2) void conv_f32(
    const float* __restrict__ x, const float* __restrict__ w,
    const int* __restrict__ bias, const int* __restrict__ qmp,
    const int* __restrict__ exp_p, const int* __restrict__ zpp,
    int* __restrict__ out, const int* __restrict__ flagp) {
    if (flagp[0] != 2) return;
    conv_body<float>(x, w, bias, qmp, exp_p, zpp, out);
}

extern "C" void kernel_launch(void* const* d_in, const int* in_sizes, int n_in,
                              void* d_out, int out_size, void* d_ws,
                              size_t ws_size, hipStream_t stream) {
    (void)in_sizes; (void)n_in; (void)ws_size; (void)out_size;
    const void* x = d_in[0];
    const void* w = d_in[1];
    const int* bias = (const int*)d_in[2];
    const int* qm = (const int*)d_in[3];
    const int* ex = (const int*)d_in[4];
    const int* zp = (const int*)d_in[5];
    int* out = (int*)d_out;
    int* flagp = (int*)d_ws;

    detect_kernel<<<1, 64, 0, stream>>>((const unsigned int*)x, flagp);
    conv_i32<<<NBLK, 256, 0, stream>>>((const int*)x, (const int*)w,
                                       bias, qm, ex, zp, out, flagp);
    conv_f32<<<NBLK, 256, 0, stream>>>((const float*)x, (const float*)w,
                                       bias, qm, ex, zp, out, flagp);
}